// Round 3
// baseline (352.751 us; speedup 1.0000x reference)
//
#include <hip/hip_runtime.h>

#define B 64
#define CL 400
#define QL 50
#define HDIM 1024
#define NEG_INF -1e30f

typedef __bf16 bf16x8v __attribute__((ext_vector_type(8)));
typedef float f32x4 __attribute__((ext_vector_type(4)));

// ---------------- workspace layout (float offsets) ----------------
// S    : [B][CL][QL] f32 raw similarity
// s2t  : [B][QL][CL] f32 softmax over c dim, transposed
// qb   : [B][QL]     f32 q.qw + bias
// s1bf : [B][448][64] bf16 softmax over q dim, j padded to 64
// qtb  : [B][H][64]  bf16 q transposed, j padded
// vtb  : [B][H][64]  bf16 s2tc transposed, j padded
#define S_OFF    0
#define S2T_OFF  1280000
#define QB_OFF   2560000
#define S1BF_OFF 2563200
#define QTB_OFF  3480704
#define VTB_OFF  5577856
// total 7,675,008 floats = 30.7 MB

__device__ inline ushort f2bf(float x) {
    uint u = __float_as_uint(x);
    uint r = (u + 0x7FFFu + ((u >> 16) & 1u)) >> 16;
    return (ushort)r;
}
__device__ inline void splitbf(float x, ushort& hi, ushort& lo) {
    ushort h = f2bf(x);
    float hf = __uint_as_float(((uint)h) << 16);
    hi = h;
    lo = f2bf(x - hf);
}

// ================= K1: qb[b][j] = q[b][j].qw + bias ======================
__global__ __launch_bounds__(256) void k_qb(
    const float* __restrict__ q, const float* __restrict__ qw,
    const float* __restrict__ bias, float* __restrict__ qb)
{
    int b = blockIdx.y;
    int j = blockIdx.x;            // 0..49
    int t = threadIdx.x;
    int h = t * 4;
    const float* qrow = q + ((size_t)b * QL + j) * HDIM;
    float4 qv  = *(const float4*)(qrow + h);
    float4 qwv = *(const float4*)(qw + h);
    float s = qv.x * qwv.x + qv.y * qwv.y + qv.z * qwv.z + qv.w * qwv.w;
    #pragma unroll
    for (int off = 32; off; off >>= 1) s += __shfl_down(s, off);
    __shared__ float red[4];
    if ((t & 63) == 0) red[t >> 6] = s;
    __syncthreads();
    if (t == 0) qb[b * QL + j] = red[0] + red[1] + red[2] + red[3] + bias[0];
}

// ================= K2: qtb[b][h][j] = bf16(q[b][j][h]), j padded to 64 ===
__global__ __launch_bounds__(256) void k_qtb(
    const float* __restrict__ q, ushort* __restrict__ qtb)
{
    int b  = blockIdx.y;
    int h0 = blockIdx.x * 64;      // 16 chunks
    int tid = threadIdx.x;
    __shared__ ushort t[64][72];
    int h4 = tid & 15, jr = tid >> 4;
    #pragma unroll
    for (int p = 0; p < 4; ++p) {
        int j = jr + p * 16;
        float4 v = make_float4(0.f, 0.f, 0.f, 0.f);
        if (j < QL) v = *(const float4*)(q + ((size_t)b * QL + j) * HDIM + h0 + h4 * 4);
        t[h4 * 4 + 0][j] = f2bf(v.x);
        t[h4 * 4 + 1][j] = f2bf(v.y);
        t[h4 * 4 + 2][j] = f2bf(v.z);
        t[h4 * 4 + 3][j] = f2bf(v.w);
    }
    __syncthreads();
    int hr = tid >> 2, seg = tid & 3;
    ushort* dst = qtb + ((size_t)b * HDIM + h0 + hr) * 64 + seg * 16;
    *(uint4*)(dst)     = *(uint4*)(&t[hr][seg * 16]);
    *(uint4*)(dst + 8) = *(uint4*)(&t[hr][seg * 16 + 8]);
}

// ================= K3: S = c @ (q*cqw | cw)^T split-bf16 MFMA + softmax ==
// 256 thr = 4 waves; tile 64(i) x 64(j; 50 q cols + col50 = c.cw); K=1024.
#define ASTR 72
__global__ __launch_bounds__(256) void k_sgemm(
    const float* __restrict__ c, const float* __restrict__ q,
    const float* __restrict__ cqw, const float* __restrict__ cw,
    const float* __restrict__ qb, const int* __restrict__ qmask,
    float* __restrict__ S, ushort* __restrict__ s1bf)
{
    int b  = blockIdx.y;
    int i0 = blockIdx.x * 64;
    int tid = threadIdx.x;
    int wid = tid >> 6, lane = tid & 63;

    __shared__ __align__(16) ushort smem_u[4 * 64 * ASTR];   // 36,864 B
    ushort* Ahi = smem_u;
    ushort* Alo = smem_u + 1 * 64 * ASTR;
    ushort* Bhi = smem_u + 2 * 64 * ASTR;
    ushort* Blo = smem_u + 3 * 64 * ASTR;
    float*  raw = (float*)smem_u;                            // [64][65] later

    const float* cb = c + (size_t)b * CL * HDIM;

    int row = tid >> 2;            // 0..63 staging row
    int kq  = (tid & 3) * 16;      // 16 k per thread
    const float* crow = (i0 + row < CL) ? cb + (size_t)(i0 + row) * HDIM : nullptr;
    const float* qsrc = (row < QL) ? q + ((size_t)b * QL + row) * HDIM : nullptr;

    int arow = (wid << 4) + (lane & 15);
    int koff = (lane >> 4) << 3;
    int brow = lane & 15;

    f32x4 acc[4] = {};
    for (int k0 = 0; k0 < HDIM; k0 += 64) {
        __syncthreads();
        #pragma unroll
        for (int f = 0; f < 4; ++f) {
            int k = kq + f * 4;
            float4 cv = crow ? *(const float4*)(crow + k0 + k) : make_float4(0.f,0.f,0.f,0.f);
            ushort4 h4, l4;
            splitbf(cv.x, h4.x, l4.x); splitbf(cv.y, h4.y, l4.y);
            splitbf(cv.z, h4.z, l4.z); splitbf(cv.w, h4.w, l4.w);
            *(ushort4*)(&Ahi[row * ASTR + k]) = h4;
            *(ushort4*)(&Alo[row * ASTR + k]) = l4;
            float4 qv = make_float4(0.f, 0.f, 0.f, 0.f);
            if (qsrc) {
                qv = *(const float4*)(qsrc + k0 + k);
                float4 w = *(const float4*)(cqw + k0 + k);
                qv.x *= w.x; qv.y *= w.y; qv.z *= w.z; qv.w *= w.w;
            } else if (row == QL) {
                qv = *(const float4*)(cw + k0 + k);
            }
            splitbf(qv.x, h4.x, l4.x); splitbf(qv.y, h4.y, l4.y);
            splitbf(qv.z, h4.z, l4.z); splitbf(qv.w, h4.w, l4.w);
            *(ushort4*)(&Bhi[row * ASTR + k]) = h4;
            *(ushort4*)(&Blo[row * ASTR + k]) = l4;
        }
        __syncthreads();
        #pragma unroll
        for (int ks = 0; ks < 64; ks += 32) {
            bf16x8v ah = *(const bf16x8v*)(&Ahi[arow * ASTR + koff + ks]);
            bf16x8v al = *(const bf16x8v*)(&Alo[arow * ASTR + koff + ks]);
            #pragma unroll
            for (int jt = 0; jt < 4; ++jt) {
                int bo = (jt * 16 + brow) * ASTR + koff + ks;
                bf16x8v bh = *(const bf16x8v*)(&Bhi[bo]);
                bf16x8v bl = *(const bf16x8v*)(&Blo[bo]);
                acc[jt] = __builtin_amdgcn_mfma_f32_16x16x32_bf16(al, bh, acc[jt], 0, 0, 0);
                acc[jt] = __builtin_amdgcn_mfma_f32_16x16x32_bf16(ah, bl, acc[jt], 0, 0, 0);
                acc[jt] = __builtin_amdgcn_mfma_f32_16x16x32_bf16(ah, bh, acc[jt], 0, 0, 0);
            }
        }
    }
    // frag -> LDS raw[64][65]
    __syncthreads();
    #pragma unroll
    for (int jt = 0; jt < 4; ++jt)
        #pragma unroll
        for (int rg = 0; rg < 4; ++rg)
            raw[((wid << 4) + ((lane >> 4) << 2) + rg) * 65 + jt * 16 + (lane & 15)] = acc[jt][rg];
    __syncthreads();
    // softmax over j for 64 rows, one row per thread
    if (tid < 64 && i0 + tid < CL) {
        int i = i0 + tid;
        float* rrow = raw + tid * 65;
        float sc = rrow[50];                    // c_i . c_weight
        const float* qbb = qb + b * QL;
        const int*   qm  = qmask + b * QL;
        float*  Srow = S + ((size_t)b * CL + i) * QL;
        ushort* s1r  = s1bf + ((size_t)b * 448 + i) * 64;
        float m = -3.4e38f;
        for (int j = 0; j < QL; ++j) {
            float s = rrow[j] + sc + qbb[j];
            Srow[j] = s;
            float sm = qm[j] ? s : NEG_INF;
            rrow[j] = sm;
            m = fmaxf(m, sm);
        }
        float z = 0.f;
        for (int j = 0; j < QL; ++j) {
            float p = __expf(rrow[j] - m);
            rrow[j] = p; z += p;
        }
        float rz = 1.f / z;
        for (int j = 0; j < QL; ++j) s1r[j] = f2bf(rrow[j] * rz);
        for (int j = QL; j < 64; ++j) s1r[j] = 0;
    }
}

// ================= K4: s2t[b][j][i] = softmax_i(S masked by c_mask) ======
__global__ __launch_bounds__(64) void k_s2(
    const float* __restrict__ S, const int* __restrict__ cmask,
    float* __restrict__ s2t)
{
    int b = blockIdx.y, j = blockIdx.x;
    int t = threadIdx.x;
    const float* Sb = S + (size_t)b * CL * QL + j;
    const int*   cm = cmask + b * CL;
    float v[7];
    float m = -3.4e38f;
    #pragma unroll
    for (int k = 0; k < 7; ++k) {
        int i = t + k * 64;
        float s = NEG_INF;
        if (i < CL) s = cm[i] ? Sb[(size_t)i * QL] : NEG_INF;
        v[k] = s;
        m = fmaxf(m, s);
    }
    #pragma unroll
    for (int off = 32; off; off >>= 1) m = fmaxf(m, __shfl_xor(m, off));
    float z = 0.f;
    #pragma unroll
    for (int k = 0; k < 7; ++k) {
        float p = (t + k * 64 < CL) ? __expf(v[k] - m) : 0.f;
        v[k] = p; z += p;
    }
    #pragma unroll
    for (int off = 32; off; off >>= 1) z += __shfl_xor(z, off);
    float rz = 1.f / z;
    float* dst = s2t + ((size_t)b * QL + j) * CL;
    #pragma unroll
    for (int k = 0; k < 7; ++k) {
        int i = t + k * 64;
        if (i < CL) dst[i] = v[k] * rz;
    }
}

// ================= K5: vtb[b][h][j] = bf16( (s2t @ c)[j][h] ) transposed =
// tile 64(j, 50 valid) x 64(h); K=400 padded to 416; bf16 MFMA
#define BSTR 40
__global__ __launch_bounds__(256) void k_s2tc(
    const float* __restrict__ s2t, const float* __restrict__ c,
    ushort* __restrict__ vtb)
{
    int b  = blockIdx.y;
    int h0 = blockIdx.x * 64;
    int tid = threadIdx.x;
    int wid = tid >> 6, lane = tid & 63;

    __shared__ __align__(16) ushort As[64 * BSTR];   // s2 [j][i]
    __shared__ __align__(16) ushort Bs[64 * BSTR];   // c^T [h][i]
    __shared__ __align__(16) ushort tr[64][72];      // transpose buffer

    const float* ab = s2t + (size_t)b * QL * CL;
    const float* cb = c   + (size_t)b * CL * HDIM;

    int arw = tid >> 2;            // staging row j
    int akq = (tid & 3) * 8;       // 8 k per thread
    int h4  = tid & 15;
    int kcb = tid >> 4;

    int frow = lane & 15;
    int koff = (lane >> 4) << 3;

    f32x4 acc[4] = {};
    for (int k0 = 0; k0 < 416; k0 += 32) {
        __syncthreads();
        #pragma unroll
        for (int f = 0; f < 2; ++f) {
            int kg = k0 + akq + f * 4;
            float4 v = (arw < QL && kg < CL) ? *(const float4*)(ab + (size_t)arw * CL + kg)
                                             : make_float4(0.f,0.f,0.f,0.f);
            ushort4 p;
            p.x = f2bf(v.x); p.y = f2bf(v.y); p.z = f2bf(v.z); p.w = f2bf(v.w);
            *(ushort4*)(&As[arw * BSTR + akq + f * 4]) = p;
        }
        #pragma unroll
        for (int it = 0; it < 2; ++it) {
            int kc = kcb + it * 16;
            int gi = k0 + kc;
            float4 v = (gi < CL) ? *(const float4*)(cb + (size_t)gi * HDIM + h0 + h4 * 4)
                                 : make_float4(0.f,0.f,0.f,0.f);
            Bs[(h4 * 4 + 0) * BSTR + kc] = f2bf(v.x);
            Bs[(h4 * 4 + 1) * BSTR + kc] = f2bf(v.y);
            Bs[(h4 * 4 + 2) * BSTR + kc] = f2bf(v.z);
            Bs[(h4 * 4 + 3) * BSTR + kc] = f2bf(v.w);
        }
        __syncthreads();
        bf16x8v a = *(const bf16x8v*)(&As[((wid << 4) + frow) * BSTR + koff]);
        #pragma unroll
        for (int ht = 0; ht < 4; ++ht) {
            bf16x8v bb = *(const bf16x8v*)(&Bs[(ht * 16 + frow) * BSTR + koff]);
            acc[ht] = __builtin_amdgcn_mfma_f32_16x16x32_bf16(a, bb, acc[ht], 0, 0, 0);
        }
    }
    // transpose [j][h] -> [h][j] bf16 and store rows of 64
    __syncthreads();
    #pragma unroll
    for (int ht = 0; ht < 4; ++ht)
        #pragma unroll
        for (int rg = 0; rg < 4; ++rg)
            tr[ht * 16 + frow][(wid << 4) + ((lane >> 4) << 2) + rg] = f2bf(acc[ht][rg]);
    __syncthreads();
    int hr = tid >> 2, seg = tid & 3;
    ushort* dst = vtb + ((size_t)b * HDIM + h0 + hr) * 64 + seg * 16;
    *(uint4*)(dst)     = *(uint4*)(&tr[hr][seg * 16]);
    *(uint4*)(dst + 8) = *(uint4*)(&tr[hr][seg * 16 + 8]);
}

// ================= K6: out = [c, a, c*a, c*t]; a = s1@q, t = s1@s2tc =====
// pure MFMA, no LDS. grid (7 i-tiles, 4 h-quarters, B); 4 waves.
__global__ __launch_bounds__(256) void k_final(
    const float* __restrict__ c, const ushort* __restrict__ s1bf,
    const ushort* __restrict__ qtb, const ushort* __restrict__ vtb,
    float* __restrict__ out)
{
    int b  = blockIdx.z;
    int i0 = blockIdx.x * 64;
    int hq = blockIdx.y;
    int tid = threadIdx.x;
    int wid = tid >> 6, lane = tid & 63;
    int frow = lane & 15;
    int kof  = (lane >> 4) << 3;

    // A fragments (independent of h): s1 rows i0 + wid*16 + frow
    const ushort* arow = s1bf + ((size_t)b * 448 + i0 + wid * 16 + frow) * 64;
    bf16x8v af0 = *(const bf16x8v*)(arow + kof);
    bf16x8v af1 = *(const bf16x8v*)(arow + 32 + kof);

    const float* cb = c + (size_t)b * CL * HDIM;
    float* ob = out + (size_t)b * CL * 4 * HDIM;

    for (int hc = hq * 4; hc < hq * 4 + 4; ++hc) {
        int h0 = hc * 64;
        f32x4 aacc[4], tacc[4];
        #pragma unroll
        for (int ht = 0; ht < 4; ++ht) {
            const ushort* qr = qtb + ((size_t)b * HDIM + h0 + ht * 16 + frow) * 64 + kof;
            const ushort* vr = vtb + ((size_t)b * HDIM + h0 + ht * 16 + frow) * 64 + kof;
            bf16x8v bq0 = *(const bf16x8v*)(qr);
            bf16x8v bq1 = *(const bf16x8v*)(qr + 32);
            bf16x8v bv0 = *(const bf16x8v*)(vr);
            bf16x8v bv1 = *(const bf16x8v*)(vr + 32);
            f32x4 z = {};
            aacc[ht] = __builtin_amdgcn_mfma_f32_16x16x32_bf16(af1, bq1,
                         __builtin_amdgcn_mfma_f32_16x16x32_bf16(af0, bq0, z, 0, 0, 0), 0, 0, 0);
            tacc[ht] = __builtin_amdgcn_mfma_f32_16x16x32_bf16(af1, bv1,
                         __builtin_amdgcn_mfma_f32_16x16x32_bf16(af0, bv0, z, 0, 0, 0), 0, 0, 0);
        }
        #pragma unroll
        for (int ht = 0; ht < 4; ++ht) {
            #pragma unroll
            for (int rg = 0; rg < 4; ++rg) {
                int gi = i0 + wid * 16 + (lane >> 4) * 4 + rg;
                if (gi < CL) {
                    int gh = h0 + ht * 16 + frow;
                    float cv = cb[(size_t)gi * HDIM + gh];
                    float av = aacc[ht][rg];
                    float tv = tacc[ht][rg];
                    size_t o = (size_t)gi * (4 * HDIM) + gh;
                    ob[o]             = cv;
                    ob[o + HDIM]      = av;
                    ob[o + 2 * HDIM]  = cv * av;
                    ob[o + 3 * HDIM]  = cv * tv;
                }
            }
        }
    }
}

extern "C" void kernel_launch(void* const* d_in, const int* in_sizes, int n_in,
                              void* d_out, int out_size, void* d_ws, size_t ws_size,
                              hipStream_t stream) {
    const float* c     = (const float*)d_in[0];
    const float* q     = (const float*)d_in[1];
    const int*   cmask = (const int*)d_in[2];
    const int*   qmask = (const int*)d_in[3];
    const float* cw    = (const float*)d_in[4];
    const float* qw    = (const float*)d_in[5];
    const float* cqw   = (const float*)d_in[6];
    const float* bias  = (const float*)d_in[7];
    float* out = (float*)d_out;
    float* ws  = (float*)d_ws;

    float*  S    = ws + S_OFF;
    float*  s2t  = ws + S2T_OFF;
    float*  qb   = ws + QB_OFF;
    ushort* s1bf = (ushort*)(ws + S1BF_OFF);
    ushort* qtb  = (ushort*)(ws + QTB_OFF);
    ushort* vtb  = (ushort*)(ws + VTB_OFF);

    k_qb   <<<dim3(QL, B), 256, 0, stream>>>(q, qw, bias, qb);
    k_qtb  <<<dim3(16, B), 256, 0, stream>>>(q, qtb);
    k_sgemm<<<dim3(7, B),  256, 0, stream>>>(c, q, cqw, cw, qb, qmask, S, s1bf);
    k_s2   <<<dim3(QL, B), 64,  0, stream>>>(S, cmask, s2t);
    k_s2tc <<<dim3(16, B), 256, 0, stream>>>(s2t, c, vtb);
    k_final<<<dim3(7, 4, B), 256, 0, stream>>>(c, s1bf, qtb, vtb, out);
}

// Round 4
// 285.835 us; speedup vs baseline: 1.2341x; 1.2341x over previous
//
#include <hip/hip_runtime.h>

#define B 64
#define CL 400
#define QL 50
#define HDIM 1024
#define NEG_INF -1e30f

typedef __bf16 bf16x8v __attribute__((ext_vector_type(8)));
typedef float f32x4 __attribute__((ext_vector_type(4)));

// ---------------- workspace layout (float offsets) ----------------
// St   : [B][QL][CL] f32 raw similarity TRANSPOSED (coalesced for col-softmax)
// s2t  : [B][QL][CL] f32 softmax over c dim, transposed
// qb   : [B][QL]     f32 q.qw + bias
// s1bf : [B][448][64] bf16 softmax over q dim, j padded to 64
// qtb  : [B][H][64]  bf16 q transposed, j padded
// vtb  : [B][H][64]  bf16 s2tc transposed, j padded
#define ST_OFF   0
#define S2T_OFF  1280000
#define QB_OFF   2560000
#define S1BF_OFF 2563200
#define QTB_OFF  3480704
#define VTB_OFF  5577856
// total 7,675,008 floats = 30.7 MB

__device__ inline ushort f2bf(float x) {
    uint u = __float_as_uint(x);
    uint r = (u + 0x7FFFu + ((u >> 16) & 1u)) >> 16;
    return (ushort)r;
}
__device__ inline void splitbf(float x, ushort& hi, ushort& lo) {
    ushort h = f2bf(x);
    float hf = __uint_as_float(((uint)h) << 16);
    hi = h;
    lo = f2bf(x - hf);
}

// ================= K1: qb[b][j] = q[b][j].qw + bias ======================
__global__ __launch_bounds__(256) void k_qb(
    const float* __restrict__ q, const float* __restrict__ qw,
    const float* __restrict__ bias, float* __restrict__ qb)
{
    int b = blockIdx.y;
    int j = blockIdx.x;            // 0..49
    int t = threadIdx.x;
    int h = t * 4;
    const float* qrow = q + ((size_t)b * QL + j) * HDIM;
    float4 qv  = *(const float4*)(qrow + h);
    float4 qwv = *(const float4*)(qw + h);
    float s = qv.x * qwv.x + qv.y * qwv.y + qv.z * qwv.z + qv.w * qwv.w;
    #pragma unroll
    for (int off = 32; off; off >>= 1) s += __shfl_down(s, off);
    __shared__ float red[4];
    if ((t & 63) == 0) red[t >> 6] = s;
    __syncthreads();
    if (t == 0) qb[b * QL + j] = red[0] + red[1] + red[2] + red[3] + bias[0];
}

// ================= K2: qtb[b][h][j] = bf16(q[b][j][h]), j padded to 64 ===
__global__ __launch_bounds__(256) void k_qtb(
    const float* __restrict__ q, ushort* __restrict__ qtb)
{
    int b  = blockIdx.y;
    int h0 = blockIdx.x * 64;      // 16 chunks
    int tid = threadIdx.x;
    __shared__ ushort t[64][72];
    int h4 = tid & 15, jr = tid >> 4;
    #pragma unroll
    for (int p = 0; p < 4; ++p) {
        int j = jr + p * 16;
        float4 v = make_float4(0.f, 0.f, 0.f, 0.f);
        if (j < QL) v = *(const float4*)(q + ((size_t)b * QL + j) * HDIM + h0 + h4 * 4);
        t[h4 * 4 + 0][j] = f2bf(v.x);
        t[h4 * 4 + 1][j] = f2bf(v.y);
        t[h4 * 4 + 2][j] = f2bf(v.z);
        t[h4 * 4 + 3][j] = f2bf(v.w);
    }
    __syncthreads();
    int hr = tid >> 2, seg = tid & 3;
    ushort* dst = qtb + ((size_t)b * HDIM + h0 + hr) * 64 + seg * 16;
    *(uint4*)(dst)     = *(uint4*)(&t[hr][seg * 16]);
    *(uint4*)(dst + 8) = *(uint4*)(&t[hr][seg * 16 + 8]);
}

// ================= K3: S = c @ (q*cqw | cw)^T split-bf16 MFMA + softmax ==
// 256 thr = 4 waves; tile 64(i) x 64(j; 50 q cols + col50 = c.cw); K=1024.
// Writes St (S transposed, coalesced) and s1 as bf16.
#define ASTR 72
__global__ __launch_bounds__(256) void k_sgemm(
    const float* __restrict__ c, const float* __restrict__ q,
    const float* __restrict__ cqw, const float* __restrict__ cw,
    const float* __restrict__ qb, const int* __restrict__ qmask,
    float* __restrict__ St, ushort* __restrict__ s1bf)
{
    int b  = blockIdx.y;
    int i0 = blockIdx.x * 64;
    int tid = threadIdx.x;
    int wid = tid >> 6, lane = tid & 63;

    __shared__ __align__(16) ushort smem_u[4 * 64 * ASTR];   // 36,864 B
    ushort* Ahi = smem_u;
    ushort* Alo = smem_u + 1 * 64 * ASTR;
    ushort* Bhi = smem_u + 2 * 64 * ASTR;
    ushort* Blo = smem_u + 3 * 64 * ASTR;
    float*  raw = (float*)smem_u;                            // [64][65] later

    const float* cb = c + (size_t)b * CL * HDIM;

    int row = tid >> 2;            // 0..63 staging row
    int kq  = (tid & 3) * 16;      // 16 k per thread
    const float* crow = (i0 + row < CL) ? cb + (size_t)(i0 + row) * HDIM : nullptr;
    const float* qsrc = (row < QL) ? q + ((size_t)b * QL + row) * HDIM : nullptr;

    int arow = (wid << 4) + (lane & 15);
    int koff = (lane >> 4) << 3;
    int brow = lane & 15;

    f32x4 acc[4] = {};
    for (int k0 = 0; k0 < HDIM; k0 += 64) {
        __syncthreads();
        #pragma unroll
        for (int f = 0; f < 4; ++f) {
            int k = kq + f * 4;
            float4 cv = crow ? *(const float4*)(crow + k0 + k) : make_float4(0.f,0.f,0.f,0.f);
            ushort4 h4, l4;
            splitbf(cv.x, h4.x, l4.x); splitbf(cv.y, h4.y, l4.y);
            splitbf(cv.z, h4.z, l4.z); splitbf(cv.w, h4.w, l4.w);
            *(ushort4*)(&Ahi[row * ASTR + k]) = h4;
            *(ushort4*)(&Alo[row * ASTR + k]) = l4;
            float4 qv = make_float4(0.f, 0.f, 0.f, 0.f);
            if (qsrc) {
                qv = *(const float4*)(qsrc + k0 + k);
                float4 w = *(const float4*)(cqw + k0 + k);
                qv.x *= w.x; qv.y *= w.y; qv.z *= w.z; qv.w *= w.w;
            } else if (row == QL) {
                qv = *(const float4*)(cw + k0 + k);
            }
            splitbf(qv.x, h4.x, l4.x); splitbf(qv.y, h4.y, l4.y);
            splitbf(qv.z, h4.z, l4.z); splitbf(qv.w, h4.w, l4.w);
            *(ushort4*)(&Bhi[row * ASTR + k]) = h4;
            *(ushort4*)(&Blo[row * ASTR + k]) = l4;
        }
        __syncthreads();
        #pragma unroll
        for (int ks = 0; ks < 64; ks += 32) {
            bf16x8v ah = *(const bf16x8v*)(&Ahi[arow * ASTR + koff + ks]);
            bf16x8v al = *(const bf16x8v*)(&Alo[arow * ASTR + koff + ks]);
            #pragma unroll
            for (int jt = 0; jt < 4; ++jt) {
                int bo = (jt * 16 + brow) * ASTR + koff + ks;
                bf16x8v bh = *(const bf16x8v*)(&Bhi[bo]);
                bf16x8v bl = *(const bf16x8v*)(&Blo[bo]);
                acc[jt] = __builtin_amdgcn_mfma_f32_16x16x32_bf16(al, bh, acc[jt], 0, 0, 0);
                acc[jt] = __builtin_amdgcn_mfma_f32_16x16x32_bf16(ah, bl, acc[jt], 0, 0, 0);
                acc[jt] = __builtin_amdgcn_mfma_f32_16x16x32_bf16(ah, bh, acc[jt], 0, 0, 0);
            }
        }
    }
    // frag -> LDS raw[64][65]
    __syncthreads();
    #pragma unroll
    for (int jt = 0; jt < 4; ++jt)
        #pragma unroll
        for (int rg = 0; rg < 4; ++rg)
            raw[((wid << 4) + ((lane >> 4) << 2) + rg) * 65 + jt * 16 + (lane & 15)] = acc[jt][rg];
    __syncthreads();
    // softmax over j for 64 rows, one row per thread
    if (tid < 64 && i0 + tid < CL) {
        int i = i0 + tid;
        float* rrow = raw + tid * 65;
        float sc = rrow[50];                    // c_i . c_weight
        const float* qbb = qb + b * QL;
        const int*   qm  = qmask + b * QL;
        float*  Stp  = St + (size_t)b * QL * CL + i;      // stride CL per j
        ushort* s1r  = s1bf + ((size_t)b * 448 + i) * 64;
        float m = -3.4e38f;
        for (int j = 0; j < QL; ++j) {
            float s = rrow[j] + sc + qbb[j];
            Stp[(size_t)j * CL] = s;                      // coalesced across threads
            float sm = qm[j] ? s : NEG_INF;
            rrow[j] = sm;
            m = fmaxf(m, sm);
        }
        float z = 0.f;
        for (int j = 0; j < QL; ++j) {
            float p = __expf(rrow[j] - m);
            rrow[j] = p; z += p;
        }
        float rz = 1.f / z;
        for (int j = 0; j < QL; ++j) s1r[j] = f2bf(rrow[j] * rz);
        for (int j = QL; j < 64; ++j) s1r[j] = 0;
    }
}

// ================= K4: s2t[b][j][i] = softmax_i(St row, masked) ==========
__global__ __launch_bounds__(64) void k_s2(
    const float* __restrict__ St, const int* __restrict__ cmask,
    float* __restrict__ s2t)
{
    int b = blockIdx.y, j = blockIdx.x;
    int t = threadIdx.x;
    const float* row = St + ((size_t)b * QL + j) * CL;
    const int*   cm  = cmask + b * CL;
    float v[7];
    float m = -3.4e38f;
    #pragma unroll
    for (int k = 0; k < 7; ++k) {
        int i = t + k * 64;
        float s = NEG_INF;
        if (i < CL) s = cm[i] ? row[i] : NEG_INF;
        v[k] = s;
        m = fmaxf(m, s);
    }
    #pragma unroll
    for (int off = 32; off; off >>= 1) m = fmaxf(m, __shfl_xor(m, off));
    float z = 0.f;
    #pragma unroll
    for (int k = 0; k < 7; ++k) {
        float p = (t + k * 64 < CL) ? __expf(v[k] - m) : 0.f;
        v[k] = p; z += p;
    }
    #pragma unroll
    for (int off = 32; off; off >>= 1) z += __shfl_xor(z, off);
    float rz = 1.f / z;
    float* dst = s2t + ((size_t)b * QL + j) * CL;
    #pragma unroll
    for (int k = 0; k < 7; ++k) {
        int i = t + k * 64;
        if (i < CL) dst[i] = v[k] * rz;
    }
}

// ================= K5: vtb[b][h][j] = bf16( (s2t @ c)[j][h] ) transposed =
#define BSTR 40
__global__ __launch_bounds__(256) void k_s2tc(
    const float* __restrict__ s2t, const float* __restrict__ c,
    ushort* __restrict__ vtb)
{
    int b  = blockIdx.y;
    int h0 = blockIdx.x * 64;
    int tid = threadIdx.x;
    int wid = tid >> 6, lane = tid & 63;

    __shared__ __align__(16) ushort As[64 * BSTR];   // s2 [j][i]
    __shared__ __align__(16) ushort Bs[64 * BSTR];   // c^T [h][i]
    __shared__ __align__(16) ushort tr[64][72];      // transpose buffer

    const float* ab = s2t + (size_t)b * QL * CL;
    const float* cb = c   + (size_t)b * CL * HDIM;

    int arw = tid >> 2;            // staging row j
    int akq = (tid & 3) * 8;       // 8 k per thread
    int h4  = tid & 15;
    int kcb = tid >> 4;

    int frow = lane & 15;
    int koff = (lane >> 4) << 3;

    f32x4 acc[4] = {};
    for (int k0 = 0; k0 < 416; k0 += 32) {
        __syncthreads();
        #pragma unroll
        for (int f = 0; f < 2; ++f) {
            int kg = k0 + akq + f * 4;
            float4 v = (arw < QL && kg < CL) ? *(const float4*)(ab + (size_t)arw * CL + kg)
                                             : make_float4(0.f,0.f,0.f,0.f);
            ushort4 p;
            p.x = f2bf(v.x); p.y = f2bf(v.y); p.z = f2bf(v.z); p.w = f2bf(v.w);
            *(ushort4*)(&As[arw * BSTR + akq + f * 4]) = p;
        }
        #pragma unroll
        for (int it = 0; it < 2; ++it) {
            int kc = kcb + it * 16;
            int gi = k0 + kc;
            float4 v = (gi < CL) ? *(const float4*)(cb + (size_t)gi * HDIM + h0 + h4 * 4)
                                 : make_float4(0.f,0.f,0.f,0.f);
            Bs[(h4 * 4 + 0) * BSTR + kc] = f2bf(v.x);
            Bs[(h4 * 4 + 1) * BSTR + kc] = f2bf(v.y);
            Bs[(h4 * 4 + 2) * BSTR + kc] = f2bf(v.z);
            Bs[(h4 * 4 + 3) * BSTR + kc] = f2bf(v.w);
        }
        __syncthreads();
        bf16x8v a = *(const bf16x8v*)(&As[((wid << 4) + frow) * BSTR + koff]);
        #pragma unroll
        for (int ht = 0; ht < 4; ++ht) {
            bf16x8v bb = *(const bf16x8v*)(&Bs[(ht * 16 + frow) * BSTR + koff]);
            acc[ht] = __builtin_amdgcn_mfma_f32_16x16x32_bf16(a, bb, acc[ht], 0, 0, 0);
        }
    }
    // transpose [j][h] -> [h][j] bf16 and store rows of 64
    __syncthreads();
    #pragma unroll
    for (int ht = 0; ht < 4; ++ht)
        #pragma unroll
        for (int rg = 0; rg < 4; ++rg)
            tr[ht * 16 + frow][(wid << 4) + ((lane >> 4) << 2) + rg] = f2bf(acc[ht][rg]);
    __syncthreads();
    int hr = tid >> 2, seg = tid & 3;
    ushort* dst = vtb + ((size_t)b * HDIM + h0 + hr) * 64 + seg * 16;
    *(uint4*)(dst)     = *(uint4*)(&tr[hr][seg * 16]);
    *(uint4*)(dst + 8) = *(uint4*)(&tr[hr][seg * 16 + 8]);
}

// ================= K6: out = [c, a, c*a, c*t]; a = s1@q, t = s1@s2tc =====
// Operand-swapped MFMA: D[m=h][n=i] so each lane holds 4 consecutive h at
// one i -> float4 c-load + float4 stores. No LDS. grid (7, 4 hq, B).
__global__ __launch_bounds__(256) void k_final(
    const float* __restrict__ c, const ushort* __restrict__ s1bf,
    const ushort* __restrict__ qtb, const ushort* __restrict__ vtb,
    float* __restrict__ out)
{
    int b  = blockIdx.z;
    int i0 = blockIdx.x * 64;
    int hq = blockIdx.y;
    int tid = threadIdx.x;
    int wid = tid >> 6, lane = tid & 63;
    int l15 = lane & 15;
    int kof = (lane >> 4) << 3;

    // B operand (n-dim = i): s1 rows i0 + wid*16 + l15
    const ushort* srow = s1bf + ((size_t)b * 448 + i0 + wid * 16 + l15) * 64;
    bf16x8v sf0 = *(const bf16x8v*)(srow + kof);
    bf16x8v sf1 = *(const bf16x8v*)(srow + 32 + kof);

    int gi = i0 + wid * 16 + l15;
    const float* cb = c + (size_t)b * CL * HDIM;
    float* ob = out + (size_t)b * CL * 4 * HDIM;

    for (int hc = hq * 4; hc < hq * 4 + 4; ++hc) {
        int h0 = hc * 64;
        f32x4 aacc[4], tacc[4];
        #pragma unroll
        for (int ht = 0; ht < 4; ++ht) {
            // A operand (m-dim = h): q^T / v^T rows h0 + ht*16 + l15
            const ushort* qr = qtb + ((size_t)b * HDIM + h0 + ht * 16 + l15) * 64 + kof;
            const ushort* vr = vtb + ((size_t)b * HDIM + h0 + ht * 16 + l15) * 64 + kof;
            bf16x8v q0 = *(const bf16x8v*)(qr);
            bf16x8v q1 = *(const bf16x8v*)(qr + 32);
            bf16x8v v0 = *(const bf16x8v*)(vr);
            bf16x8v v1 = *(const bf16x8v*)(vr + 32);
            f32x4 z = {};
            aacc[ht] = __builtin_amdgcn_mfma_f32_16x16x32_bf16(q1, sf1,
                         __builtin_amdgcn_mfma_f32_16x16x32_bf16(q0, sf0, z, 0, 0, 0), 0, 0, 0);
            tacc[ht] = __builtin_amdgcn_mfma_f32_16x16x32_bf16(v1, sf1,
                         __builtin_amdgcn_mfma_f32_16x16x32_bf16(v0, sf0, z, 0, 0, 0), 0, 0, 0);
        }
        if (gi < CL) {
            #pragma unroll
            for (int ht = 0; ht < 4; ++ht) {
                int gh = h0 + ht * 16 + ((lane >> 4) << 2);
                float4 cv = *(const float4*)(cb + (size_t)gi * HDIM + gh);
                float4 av, cav, ctv;
                av.x  = aacc[ht][0]; av.y  = aacc[ht][1];
                av.z  = aacc[ht][2]; av.w  = aacc[ht][3];
                cav.x = cv.x * av.x; cav.y = cv.y * av.y;
                cav.z = cv.z * av.z; cav.w = cv.w * av.w;
                ctv.x = cv.x * tacc[ht][0]; ctv.y = cv.y * tacc[ht][1];
                ctv.z = cv.z * tacc[ht][2]; ctv.w = cv.w * tacc[ht][3];
                size_t o = (size_t)gi * (4 * HDIM) + gh;
                *(float4*)(ob + o)            = cv;
                *(float4*)(ob + o + HDIM)     = av;
                *(float4*)(ob + o + 2 * HDIM) = cav;
                *(float4*)(ob + o + 3 * HDIM) = ctv;
            }
        }
    }
}

extern "C" void kernel_launch(void* const* d_in, const int* in_sizes, int n_in,
                              void* d_out, int out_size, void* d_ws, size_t ws_size,
                              hipStream_t stream) {
    const float* c     = (const float*)d_in[0];
    const float* q     = (const float*)d_in[1];
    const int*   cmask = (const int*)d_in[2];
    const int*   qmask = (const int*)d_in[3];
    const float* cw    = (const float*)d_in[4];
    const float* qw    = (const float*)d_in[5];
    const float* cqw   = (const float*)d_in[6];
    const float* bias  = (const float*)d_in[7];
    float* out = (float*)d_out;
    float* ws  = (float*)d_ws;

    float*  St   = ws + ST_OFF;
    float*  s2t  = ws + S2T_OFF;
    float*  qb   = ws + QB_OFF;
    ushort* s1bf = (ushort*)(ws + S1BF_OFF);
    ushort* qtb  = (ushort*)(ws + QTB_OFF);
    ushort* vtb  = (ushort*)(ws + VTB_OFF);

    k_qb   <<<dim3(QL, B), 256, 0, stream>>>(q, qw, bias, qb);
    k_qtb  <<<dim3(16, B), 256, 0, stream>>>(q, qtb);
    k_sgemm<<<dim3(7, B),  256, 0, stream>>>(c, q, cqw, cw, qb, qmask, St, s1bf);
    k_s2   <<<dim3(QL, B), 64,  0, stream>>>(St, cmask, s2t);
    k_s2tc <<<dim3(16, B), 256, 0, stream>>>(s2t, c, vtb);
    k_final<<<dim3(7, 4, B), 256, 0, stream>>>(c, s1bf, qtb, vtb, out);
}

// Round 5
// 237.797 us; speedup vs baseline: 1.4834x; 1.2020x over previous
//
#include <hip/hip_runtime.h>

#define B 64
#define CL 400
#define QL 50
#define HDIM 1024
#define NEG_INF -1e30f

typedef __bf16 bf16x8v __attribute__((ext_vector_type(8)));
typedef float f32x4 __attribute__((ext_vector_type(4)));

// ---------------- workspace layout (float offsets) ----------------
// St   : [B][QL][CL] f32 raw similarity transposed
// s2t  : [B][QL][CL] f32 softmax over c dim, transposed
// qb   : [B][QL]     f32 q.qw + bias
// s1bf : [B][448][64] bf16 s1, j padded to 64
// qtb  : [B][H][64]  bf16 q transposed, j padded
// qhi/qlo : [B][52][H] bf16 split of q*cqw (rows 0..49), cw (row 50), 0 (row 51)
// vtb  : [B][H][64]  bf16 s2tc transposed -- ALIASES qhi (dead after k_sgemm)
#define ST_OFF   0
#define S2T_OFF  1280000
#define QB_OFF   2560000
#define S1BF_OFF 2563200
#define QTB_OFF  3480704
#define QHI_OFF  5577856
#define QLO_OFF  7281792
// total 8,985,728 floats = 35.9 MB; vtb aliases QHI_OFF (needs 2,097,152 fl)

__device__ inline ushort f2bf(float x) {
    uint u = __float_as_uint(x);
    uint r = (u + 0x7FFFu + ((u >> 16) & 1u)) >> 16;
    return (ushort)r;
}
__device__ inline void splitbf(float x, ushort& hi, ushort& lo) {
    ushort h = f2bf(x);
    float hf = __uint_as_float(((uint)h) << 16);
    hi = h;
    lo = f2bf(x - hf);
}

// ========== K1: qhi/qlo = split(q*cqw | cw | 0), qb = q.qw + bias ========
__global__ __launch_bounds__(256) void k_qsplit(
    const float* __restrict__ q, const float* __restrict__ qw,
    const float* __restrict__ cqw, const float* __restrict__ cw,
    const float* __restrict__ bias, ushort* __restrict__ qhi,
    ushort* __restrict__ qlo, float* __restrict__ qb)
{
    int b = blockIdx.y;
    int j = blockIdx.x;            // 0..51
    int t = threadIdx.x;
    int h = t * 4;
    ushort* dh = qhi + ((size_t)b * 52 + j) * HDIM + h;
    ushort* dl = qlo + ((size_t)b * 52 + j) * HDIM + h;
    if (j >= QL) {
        ushort4 hh = {0, 0, 0, 0}, ll = {0, 0, 0, 0};
        if (j == QL) {
            float4 w = *(const float4*)(cw + h);
            splitbf(w.x, hh.x, ll.x); splitbf(w.y, hh.y, ll.y);
            splitbf(w.z, hh.z, ll.z); splitbf(w.w, hh.w, ll.w);
        }
        *(ushort4*)dh = hh; *(ushort4*)dl = ll;
        return;
    }
    float4 qv = *(const float4*)(q + ((size_t)b * QL + j) * HDIM + h);
    float4 w  = *(const float4*)(cqw + h);
    ushort4 hh, ll;
    splitbf(qv.x * w.x, hh.x, ll.x); splitbf(qv.y * w.y, hh.y, ll.y);
    splitbf(qv.z * w.z, hh.z, ll.z); splitbf(qv.w * w.w, hh.w, ll.w);
    *(ushort4*)dh = hh; *(ushort4*)dl = ll;
    float4 ww = *(const float4*)(qw + h);
    float s = qv.x * ww.x + qv.y * ww.y + qv.z * ww.z + qv.w * ww.w;
    #pragma unroll
    for (int off = 32; off; off >>= 1) s += __shfl_down(s, off);
    __shared__ float red[4];
    if ((t & 63) == 0) red[t >> 6] = s;
    __syncthreads();
    if (t == 0) qb[b * QL + j] = red[0] + red[1] + red[2] + red[3] + bias[0];
}

// ========== K2: qtb[b][h][j] = bf16(q[b][j][h]), j padded to 64 ==========
__global__ __launch_bounds__(256) void k_qtb(
    const float* __restrict__ q, ushort* __restrict__ qtb)
{
    int b  = blockIdx.y;
    int h0 = blockIdx.x * 64;
    int tid = threadIdx.x;
    __shared__ ushort t[64][72];
    int h4 = tid & 15, jr = tid >> 4;
    #pragma unroll
    for (int p = 0; p < 4; ++p) {
        int j = jr + p * 16;
        float4 v = make_float4(0.f, 0.f, 0.f, 0.f);
        if (j < QL) v = *(const float4*)(q + ((size_t)b * QL + j) * HDIM + h0 + h4 * 4);
        t[h4 * 4 + 0][j] = f2bf(v.x);
        t[h4 * 4 + 1][j] = f2bf(v.y);
        t[h4 * 4 + 2][j] = f2bf(v.z);
        t[h4 * 4 + 3][j] = f2bf(v.w);
    }
    __syncthreads();
    int hr = tid >> 2, seg = tid & 3;
    ushort* dst = qtb + ((size_t)b * HDIM + h0 + hr) * 64 + seg * 16;
    *(uint4*)(dst)     = *(uint4*)(&t[hr][seg * 16]);
    *(uint4*)(dst + 8) = *(uint4*)(&t[hr][seg * 16 + 8]);
}

// ========== K3: S = ch@(qh+ql)^T (2-term MFMA) + fused softmax ===========
// tile 64(i) x 64(j; 50 q + col50 = c.cw); K=1024 in chunks of 64.
#define ASTR 72
__global__ __launch_bounds__(256) void k_sgemm(
    const float* __restrict__ c, const ushort* __restrict__ qhi,
    const ushort* __restrict__ qlo, const float* __restrict__ qb,
    const int* __restrict__ qmask,
    float* __restrict__ St, ushort* __restrict__ s1bf)
{
    int b  = blockIdx.y;
    int i0 = blockIdx.x * 64;
    int tid = threadIdx.x;
    int wid = tid >> 6, lane = tid & 63;

    __shared__ __align__(16) ushort smem_u[3 * 64 * ASTR];   // 27,648 B
    ushort* Ah = smem_u;
    ushort* Bh = smem_u + 1 * 64 * ASTR;
    ushort* Bl = smem_u + 2 * 64 * ASTR;
    float*  raw = (float*)smem_u;                            // [64][65] later

    const float* cb = c + (size_t)b * CL * HDIM;

    int row = tid >> 2;            // 0..63 staging row
    int kq  = (tid & 3) * 16;      // 16 k per thread
    const float*  crow = (i0 + row < CL) ? cb + (size_t)(i0 + row) * HDIM : nullptr;
    const ushort* qhr  = (row < 52) ? qhi + ((size_t)b * 52 + row) * HDIM : nullptr;
    const ushort* qlr  = (row < 52) ? qlo + ((size_t)b * 52 + row) * HDIM : nullptr;

    // rows 52..63 of B are always zero: write once before the loop
    if (row >= 52) {
        ushort4 z = {0, 0, 0, 0};
        #pragma unroll
        for (int f = 0; f < 4; ++f) {
            *(ushort4*)(&Bh[row * ASTR + kq + f * 4]) = z;
            *(ushort4*)(&Bl[row * ASTR + kq + f * 4]) = z;
        }
    }

    int arow = (wid << 4) + (lane & 15);
    int koff = (lane >> 4) << 3;
    int brow = lane & 15;

    f32x4 acc[4] = {};
    for (int k0 = 0; k0 < HDIM; k0 += 64) {
        __syncthreads();
        #pragma unroll
        for (int f = 0; f < 4; ++f) {
            int k = kq + f * 4;
            float4 cv = crow ? *(const float4*)(crow + k0 + k) : make_float4(0.f,0.f,0.f,0.f);
            ushort4 h4;
            h4.x = f2bf(cv.x); h4.y = f2bf(cv.y); h4.z = f2bf(cv.z); h4.w = f2bf(cv.w);
            *(ushort4*)(&Ah[row * ASTR + k]) = h4;
        }
        if (qhr) {
            *(uint4*)(&Bh[row * ASTR + kq])     = *(const uint4*)(qhr + k0 + kq);
            *(uint4*)(&Bh[row * ASTR + kq + 8]) = *(const uint4*)(qhr + k0 + kq + 8);
            *(uint4*)(&Bl[row * ASTR + kq])     = *(const uint4*)(qlr + k0 + kq);
            *(uint4*)(&Bl[row * ASTR + kq + 8]) = *(const uint4*)(qlr + k0 + kq + 8);
        }
        __syncthreads();
        #pragma unroll
        for (int ks = 0; ks < 64; ks += 32) {
            bf16x8v ah = *(const bf16x8v*)(&Ah[arow * ASTR + koff + ks]);
            #pragma unroll
            for (int jt = 0; jt < 4; ++jt) {
                int bo = (jt * 16 + brow) * ASTR + koff + ks;
                bf16x8v bh = *(const bf16x8v*)(&Bh[bo]);
                bf16x8v bl = *(const bf16x8v*)(&Bl[bo]);
                acc[jt] = __builtin_amdgcn_mfma_f32_16x16x32_bf16(ah, bl, acc[jt], 0, 0, 0);
                acc[jt] = __builtin_amdgcn_mfma_f32_16x16x32_bf16(ah, bh, acc[jt], 0, 0, 0);
            }
        }
    }
    // frag -> LDS raw[64][65]
    __syncthreads();
    #pragma unroll
    for (int jt = 0; jt < 4; ++jt)
        #pragma unroll
        for (int rg = 0; rg < 4; ++rg)
            raw[((wid << 4) + ((lane >> 4) << 2) + rg) * 65 + jt * 16 + (lane & 15)] = acc[jt][rg];
    __syncthreads();
    // softmax over j for 64 rows, one row per thread
    if (tid < 64 && i0 + tid < CL) {
        int i = i0 + tid;
        float* rrow = raw + tid * 65;
        float sc = rrow[50];                    // c_i . c_weight
        const float* qbb = qb + b * QL;
        const int*   qm  = qmask + b * QL;
        float*  Stp  = St + (size_t)b * QL * CL + i;      // stride CL per j
        ushort* s1r  = s1bf + ((size_t)b * 448 + i) * 64;
        float m = -3.4e38f;
        for (int j = 0; j < QL; ++j) {
            float s = rrow[j] + sc + qbb[j];
            Stp[(size_t)j * CL] = s;                      // coalesced across threads
            float sm = qm[j] ? s : NEG_INF;
            rrow[j] = sm;
            m = fmaxf(m, sm);
        }
        float z = 0.f;
        for (int j = 0; j < QL; ++j) {
            float p = __expf(rrow[j] - m);
            rrow[j] = p; z += p;
        }
        float rz = 1.f / z;
        for (int j = 0; j < QL; ++j) s1r[j] = f2bf(rrow[j] * rz);
        for (int j = QL; j < 64; ++j) s1r[j] = 0;
    }
}

// ========== K4: s2t[b][j][i] = softmax_i(St row, masked) =================
__global__ __launch_bounds__(64) void k_s2(
    const float* __restrict__ St, const int* __restrict__ cmask,
    float* __restrict__ s2t)
{
    int b = blockIdx.y, j = blockIdx.x;
    int t = threadIdx.x;
    const float* row = St + ((size_t)b * QL + j) * CL;
    const int*   cm  = cmask + b * CL;
    float v[7];
    float m = -3.4e38f;
    #pragma unroll
    for (int k = 0; k < 7; ++k) {
        int i = t + k * 64;
        float s = NEG_INF;
        if (i < CL) s = cm[i] ? row[i] : NEG_INF;
        v[k] = s;
        m = fmaxf(m, s);
    }
    #pragma unroll
    for (int off = 32; off; off >>= 1) m = fmaxf(m, __shfl_xor(m, off));
    float z = 0.f;
    #pragma unroll
    for (int k = 0; k < 7; ++k) {
        float p = (t + k * 64 < CL) ? __expf(v[k] - m) : 0.f;
        v[k] = p; z += p;
    }
    #pragma unroll
    for (int off = 32; off; off >>= 1) z += __shfl_xor(z, off);
    float rz = 1.f / z;
    float* dst = s2t + ((size_t)b * QL + j) * CL;
    #pragma unroll
    for (int k = 0; k < 7; ++k) {
        int i = t + k * 64;
        if (i < CL) dst[i] = v[k] * rz;
    }
}

// ========== K5: vtb[b][h][j] = bf16( (s2t @ c)[j][h] ) transposed ========
#define BSTR 40
__global__ __launch_bounds__(256) void k_s2tc(
    const float* __restrict__ s2t, const float* __restrict__ c,
    ushort* __restrict__ vtb)
{
    int b  = blockIdx.y;
    int h0 = blockIdx.x * 64;
    int tid = threadIdx.x;
    int wid = tid >> 6, lane = tid & 63;

    __shared__ __align__(16) ushort As[64 * BSTR];   // s2 [j][i]
    __shared__ __align__(16) ushort Bs[64 * BSTR];   // c^T [h][i]
    __shared__ __align__(16) ushort tr[64][72];      // transpose buffer

    const float* ab = s2t + (size_t)b * QL * CL;
    const float* cb = c   + (size_t)b * CL * HDIM;

    int arw = tid >> 2;            // staging row j
    int akq = (tid & 3) * 8;       // 8 k per thread
    int h4  = tid & 15;
    int kcb = tid >> 4;

    int frow = lane & 15;
    int koff = (lane >> 4) << 3;

    f32x4 acc[4] = {};
    for (int k0 = 0; k0 < 416; k0 += 32) {
        __syncthreads();
        #pragma unroll
        for (int f = 0; f < 2; ++f) {
            int kg = k0 + akq + f * 4;
            float4 v = (arw < QL && kg < CL) ? *(const float4*)(ab + (size_t)arw * CL + kg)
                                             : make_float4(0.f,0.f,0.f,0.f);
            ushort4 p;
            p.x = f2bf(v.x); p.y = f2bf(v.y); p.z = f2bf(v.z); p.w = f2bf(v.w);
            *(ushort4*)(&As[arw * BSTR + akq + f * 4]) = p;
        }
        #pragma unroll
        for (int it = 0; it < 2; ++it) {
            int kc = kcb + it * 16;
            int gi = k0 + kc;
            float4 v = (gi < CL) ? *(const float4*)(cb + (size_t)gi * HDIM + h0 + h4 * 4)
                                 : make_float4(0.f,0.f,0.f,0.f);
            Bs[(h4 * 4 + 0) * BSTR + kc] = f2bf(v.x);
            Bs[(h4 * 4 + 1) * BSTR + kc] = f2bf(v.y);
            Bs[(h4 * 4 + 2) * BSTR + kc] = f2bf(v.z);
            Bs[(h4 * 4 + 3) * BSTR + kc] = f2bf(v.w);
        }
        __syncthreads();
        bf16x8v a = *(const bf16x8v*)(&As[((wid << 4) + frow) * BSTR + koff]);
        #pragma unroll
        for (int ht = 0; ht < 4; ++ht) {
            bf16x8v bb = *(const bf16x8v*)(&Bs[(ht * 16 + frow) * BSTR + koff]);
            acc[ht] = __builtin_amdgcn_mfma_f32_16x16x32_bf16(a, bb, acc[ht], 0, 0, 0);
        }
    }
    // transpose [j][h] -> [h][j] bf16 and store rows of 64
    __syncthreads();
    #pragma unroll
    for (int ht = 0; ht < 4; ++ht)
        #pragma unroll
        for (int rg = 0; rg < 4; ++rg)
            tr[ht * 16 + frow][(wid << 4) + ((lane >> 4) << 2) + rg] = f2bf(acc[ht][rg]);
    __syncthreads();
    int hr = tid >> 2, seg = tid & 3;
    ushort* dst = vtb + ((size_t)b * HDIM + h0 + hr) * 64 + seg * 16;
    *(uint4*)(dst)     = *(uint4*)(&tr[hr][seg * 16]);
    *(uint4*)(dst + 8) = *(uint4*)(&tr[hr][seg * 16 + 8]);
}

// ========== K6: out = [c, a, c*a, c*t]; one 64x64 (i,h) tile per block ===
// A(m=h) from LDS-staged qtb/vtb tile; B(n=i) = s1 frags from global.
// c prefetched before staging so HBM latency hides under stage+MFMA.
__global__ __launch_bounds__(256) void k_final(
    const float* __restrict__ c, const ushort* __restrict__ s1bf,
    const ushort* __restrict__ qtb, const ushort* __restrict__ vtb,
    float* __restrict__ out)
{
    int b  = blockIdx.z;
    int i0 = blockIdx.x * 64;
    int h0 = blockIdx.y * 64;
    int tid = threadIdx.x;
    int wid = tid >> 6, lane = tid & 63;
    int l15 = lane & 15;
    int kof = (lane >> 4) << 3;
    int ghb = (lane >> 4) << 2;

    __shared__ __align__(16) ushort qsm[64 * 72];
    __shared__ __align__(16) ushort vsm[64 * 72];

    int gi = i0 + wid * 16 + l15;
    const float* cb = c + (size_t)b * CL * HDIM;

    // prefetch c for the epilogue (independent of everything below)
    float4 cv[4];
    if (gi < CL) {
        #pragma unroll
        for (int ht = 0; ht < 4; ++ht)
            cv[ht] = *(const float4*)(cb + (size_t)gi * HDIM + h0 + ht * 16 + ghb);
    }

    // s1 B-fragments from global (L2-resident)
    const ushort* srow = s1bf + ((size_t)b * 448 + i0 + wid * 16 + l15) * 64;
    bf16x8v sf0 = *(const bf16x8v*)(srow + kof);
    bf16x8v sf1 = *(const bf16x8v*)(srow + 32 + kof);

    // stage q/v tiles: 64 h-rows x 64 j, 128B per row
    {
        int row = tid >> 2, seg = tid & 3;
        const ushort* qsrc = qtb + ((size_t)b * HDIM + h0 + row) * 64 + seg * 16;
        const ushort* vsrc = vtb + ((size_t)b * HDIM + h0 + row) * 64 + seg * 16;
        *(uint4*)(&qsm[row * 72 + seg * 16])     = *(const uint4*)(qsrc);
        *(uint4*)(&qsm[row * 72 + seg * 16 + 8]) = *(const uint4*)(qsrc + 8);
        *(uint4*)(&vsm[row * 72 + seg * 16])     = *(const uint4*)(vsrc);
        *(uint4*)(&vsm[row * 72 + seg * 16 + 8]) = *(const uint4*)(vsrc + 8);
    }
    __syncthreads();

    float* ob = out + (size_t)b * CL * 4 * HDIM;
    #pragma unroll
    for (int ht = 0; ht < 4; ++ht) {
        int ar = (ht * 16 + l15) * 72;
        bf16x8v q0 = *(const bf16x8v*)(&qsm[ar + kof]);
        bf16x8v q1 = *(const bf16x8v*)(&qsm[ar + 32 + kof]);
        bf16x8v v0 = *(const bf16x8v*)(&vsm[ar + kof]);
        bf16x8v v1 = *(const bf16x8v*)(&vsm[ar + 32 + kof]);
        f32x4 z = {};
        f32x4 aacc = __builtin_amdgcn_mfma_f32_16x16x32_bf16(q1, sf1,
                       __builtin_amdgcn_mfma_f32_16x16x32_bf16(q0, sf0, z, 0, 0, 0), 0, 0, 0);
        f32x4 tacc = __builtin_amdgcn_mfma_f32_16x16x32_bf16(v1, sf1,
                       __builtin_amdgcn_mfma_f32_16x16x32_bf16(v0, sf0, z, 0, 0, 0), 0, 0, 0);
        if (gi < CL) {
            int gh = h0 + ht * 16 + ghb;
            float4 av, cav, ctv;
            av.x  = aacc[0]; av.y  = aacc[1]; av.z  = aacc[2]; av.w  = aacc[3];
            cav.x = cv[ht].x * av.x; cav.y = cv[ht].y * av.y;
            cav.z = cv[ht].z * av.z; cav.w = cv[ht].w * av.w;
            ctv.x = cv[ht].x * tacc[0]; ctv.y = cv[ht].y * tacc[1];
            ctv.z = cv[ht].z * tacc[2]; ctv.w = cv[ht].w * tacc[3];
            size_t o = (size_t)gi * (4 * HDIM) + gh;
            *(float4*)(ob + o)            = cv[ht];
            *(float4*)(ob + o + HDIM)     = av;
            *(float4*)(ob + o + 2 * HDIM) = cav;
            *(float4*)(ob + o + 3 * HDIM) = ctv;
        }
    }
}

extern "C" void kernel_launch(void* const* d_in, const int* in_sizes, int n_in,
                              void* d_out, int out_size, void* d_ws, size_t ws_size,
                              hipStream_t stream) {
    const float* c     = (const float*)d_in[0];
    const float* q     = (const float*)d_in[1];
    const int*   cmask = (const int*)d_in[2];
    const int*   qmask = (const int*)d_in[3];
    const float* cw    = (const float*)d_in[4];
    const float* qw    = (const float*)d_in[5];
    const float* cqw   = (const float*)d_in[6];
    const float* bias  = (const float*)d_in[7];
    float* out = (float*)d_out;
    float* ws  = (float*)d_ws;

    float*  St   = ws + ST_OFF;
    float*  s2t  = ws + S2T_OFF;
    float*  qb   = ws + QB_OFF;
    ushort* s1bf = (ushort*)(ws + S1BF_OFF);
    ushort* qtb  = (ushort*)(ws + QTB_OFF);
    ushort* qhi  = (ushort*)(ws + QHI_OFF);
    ushort* qlo  = (ushort*)(ws + QLO_OFF);
    ushort* vtb  = (ushort*)(ws + QHI_OFF);   // alias: qhi dead after k_sgemm

    k_qsplit<<<dim3(52, B), 256, 0, stream>>>(q, qw, cqw, cw, bias, qhi, qlo, qb);
    k_qtb   <<<dim3(16, B), 256, 0, stream>>>(q, qtb);
    k_sgemm <<<dim3(7, B),  256, 0, stream>>>(c, qhi, qlo, qb, qmask, St, s1bf);
    k_s2    <<<dim3(QL, B), 64,  0, stream>>>(St, cmask, s2t);
    k_s2tc  <<<dim3(16, B), 256, 0, stream>>>(s2t, c, vtb);
    k_final <<<dim3(7, 16, B), 256, 0, stream>>>(c, s1bf, qtb, vtb, out);
}